// Round 6
// baseline (163.110 us; speedup 1.0000x reference)
//
#include <hip/hip_runtime.h>
#include <math.h>

#define T_ 30
#define C_ 512
#define N_ 784      // 28*28 = 49 strips of 16
#define NP_ 832     // xh/xl row count per t (13 tiles of 64)
#define NA_ 800     // aT / xbn n-pitch (25 ksteps of 32)
#define EPSV 1e-12f

typedef __attribute__((ext_vector_type(8))) short bf16x8;
typedef __attribute__((ext_vector_type(4))) float f32x4;

__device__ __forceinline__ unsigned short f2bf(float f) {
    union { float f; unsigned int u; } v; v.f = f;
    unsigned int r = (v.u + 0x7FFFu + ((v.u >> 16) & 1u)) >> 16;  // RNE
    return (unsigned short)r;
}
__device__ __forceinline__ float bf2f(unsigned short h) {
    union { unsigned int u; float f; } v; v.u = ((unsigned int)h) << 16;
    return v.f;
}

// wh/wl: split-precision bf16 of w, layout [k][c]
__global__ void k_prep(const float* __restrict__ w, unsigned short* __restrict__ wh,
                       unsigned short* __restrict__ wl) {
    int idx = blockIdx.x * 256 + threadIdx.x;  // 0..32767
    float v = w[idx];
    unsigned short h = f2bf(v);
    wh[idx] = h;
    wl[idx] = f2bf(v - bf2f(h));
}

// One-shot transpose/convert + sumsq. grid (13 n-tiles, 8 c-tiles, 30 t), 256 thr.
// xh/xl [t][n:832][c:512] bf16 hi/lo (zero rows n>=784)
// xbn   [t][c][n:800] bf16          (zero cols n in [784,800))
// sumsq[t][n] += partial (atomics)
__global__ __launch_bounds__(256) void k_trans(
    const float* __restrict__ x, unsigned short* __restrict__ xh,
    unsigned short* __restrict__ xl, unsigned short* __restrict__ xbn,
    float* __restrict__ sumsq)
{
    __shared__ float sx[64][65];
    __shared__ float wred[4][64];
    int n0 = blockIdx.x * 64, c0 = blockIdx.y * 64, t = blockIdx.z;
    int tid = threadIdx.x;
    int cr = tid >> 4, li = tid & 15;   // cr: 16 c-rows/wave-group, li: n-quad
    int w = tid >> 6;
    float ss[4] = {0.f, 0.f, 0.f, 0.f};

    #pragma unroll
    for (int j = 0; j < 4; ++j) {
        int cl = j * 16 + cr;
        int n = n0 + li * 4;
        float4 q = make_float4(0.f, 0.f, 0.f, 0.f);
        if (n < N_)  // N_ multiple of 4: full float4 or nothing
            q = *reinterpret_cast<const float4*>(x + ((size_t)t * C_ + c0 + cl) * N_ + n);
        ss[0] = fmaf(q.x, q.x, ss[0]); ss[1] = fmaf(q.y, q.y, ss[1]);
        ss[2] = fmaf(q.z, q.z, ss[2]); ss[3] = fmaf(q.w, q.w, ss[3]);
        sx[cl][li * 4 + 0] = q.x; sx[cl][li * 4 + 1] = q.y;
        sx[cl][li * 4 + 2] = q.z; sx[cl][li * 4 + 3] = q.w;
    }
    #pragma unroll
    for (int i = 0; i < 4; ++i) {
        ss[i] += __shfl_xor(ss[i], 16, 64);
        ss[i] += __shfl_xor(ss[i], 32, 64);
    }
    if (((tid >> 4) & 3) == 0) {
        wred[w][li * 4 + 0] = ss[0]; wred[w][li * 4 + 1] = ss[1];
        wred[w][li * 4 + 2] = ss[2]; wred[w][li * 4 + 3] = ss[3];
    }
    __syncthreads();
    if (tid < 64 && n0 + tid < N_) {
        float s = wred[0][tid] + wred[1][tid] + wred[2][tid] + wred[3][tid];
        atomicAdd(&sumsq[t * N_ + n0 + tid], s);
    }
    // xh/xl [n][c]: thread -> c-seg li2*4, n-rows nr + j*16  (8 B coalesced stores)
    {
        int li2 = tid & 15, nr = tid >> 4;
        #pragma unroll
        for (int j = 0; j < 4; ++j) {
            int nl = nr + j * 16;
            float v0 = sx[li2 * 4 + 0][nl], v1 = sx[li2 * 4 + 1][nl];
            float v2 = sx[li2 * 4 + 2][nl], v3 = sx[li2 * 4 + 3][nl];
            ushort4 h, l;
            h.x = f2bf(v0); l.x = f2bf(v0 - bf2f(h.x));
            h.y = f2bf(v1); l.y = f2bf(v1 - bf2f(h.y));
            h.z = f2bf(v2); l.z = f2bf(v2 - bf2f(h.z));
            h.w = f2bf(v3); l.w = f2bf(v3 - bf2f(h.w));
            size_t o = ((size_t)t * NP_ + n0 + nl) * C_ + c0 + li2 * 4;
            *reinterpret_cast<ushort4*>(xh + o) = h;
            *reinterpret_cast<ushort4*>(xl + o) = l;
        }
    }
    // xbn [c][n]: thread -> c-row j*16+cr, n-seg li*4
    #pragma unroll
    for (int j = 0; j < 4; ++j) {
        int cl = j * 16 + cr;
        int n = n0 + li * 4;
        if (n < NA_) {
            ushort4 h;
            h.x = f2bf(sx[cl][li * 4 + 0]); h.y = f2bf(sx[cl][li * 4 + 1]);
            h.z = f2bf(sx[cl][li * 4 + 2]); h.w = f2bf(sx[cl][li * 4 + 3]);
            *reinterpret_cast<ushort4*>(xbn + ((size_t)t * C_ + c0 + cl) * NA_ + n) = h;
        }
    }
}

// logits (3-product split-bf16 MFMA, B straight from global xh/xl) + softmax + aT + asum.
// grid (49, 30), 256 thr. Block: 16 n x 64 k; c-reduction split over 4 waves (128 c each).
__global__ __launch_bounds__(256) void k_assign(
    const unsigned short* __restrict__ xh, const unsigned short* __restrict__ xl,
    const unsigned short* __restrict__ wh, const unsigned short* __restrict__ wl,
    const float* __restrict__ b, const float* __restrict__ sumsq,
    unsigned short* __restrict__ aT, float* __restrict__ asum)
{
    __shared__ float red[4 * 16 * 68];   // [w][n][k] partials, 17408 B
    int t = blockIdx.y, n0 = blockIdx.x * 16;
    int tid = threadIdx.x;
    int w = tid >> 6, L = tid & 63, lid = L & 15, quad = L >> 4;
    int n_lane = n0 + lid;

    f32x4 acc[4];
    #pragma unroll
    for (int mt = 0; mt < 4; ++mt)
        #pragma unroll
        for (int r = 0; r < 4; ++r) acc[mt][r] = 0.f;

    const unsigned short* bp  = xh + ((size_t)t * NP_ + n_lane) * C_ + w * 128 + quad * 8;
    const unsigned short* blp = xl + ((size_t)t * NP_ + n_lane) * C_ + w * 128 + quad * 8;

    #pragma unroll
    for (int ks = 0; ks < 4; ++ks) {
        bf16x8 bh = *reinterpret_cast<const bf16x8*>(bp + ks * 32);
        bf16x8 bl = *reinterpret_cast<const bf16x8*>(blp + ks * 32);
        int cs = w * 128 + ks * 32 + quad * 8;
        #pragma unroll
        for (int mt = 0; mt < 4; ++mt) {
            bf16x8 ah = *reinterpret_cast<const bf16x8*>(wh + (size_t)(mt * 16 + lid) * C_ + cs);
            bf16x8 al = *reinterpret_cast<const bf16x8*>(wl + (size_t)(mt * 16 + lid) * C_ + cs);
            acc[mt] = __builtin_amdgcn_mfma_f32_16x16x32_bf16(ah, bh, acc[mt], 0, 0, 0);
            acc[mt] = __builtin_amdgcn_mfma_f32_16x16x32_bf16(al, bh, acc[mt], 0, 0, 0);
            acc[mt] = __builtin_amdgcn_mfma_f32_16x16x32_bf16(ah, bl, acc[mt], 0, 0, 0);
        }
    }
    {
        float* rp = red + w * 1088;
        #pragma unroll
        for (int mt = 0; mt < 4; ++mt)
            *reinterpret_cast<f32x4*>(&rp[lid * 68 + mt * 16 + quad * 4]) = acc[mt];
    }
    __syncthreads();

    // softmax: wave w handles n rows w*4..w*4+3; lane L = k
    float bk = b[L];
    float asl = 0.f;
    unsigned short av[4];
    #pragma unroll
    for (int i = 0; i < 4; ++i) {
        int n = w * 4 + i;
        float v = red[0 * 1088 + n * 68 + L] + red[1 * 1088 + n * 68 + L]
                + red[2 * 1088 + n * 68 + L] + red[3 * 1088 + n * 68 + L];
        float s = sumsq[t * N_ + n0 + n];          // wave-uniform -> scalar load
        float inv = 1.0f / fmaxf(sqrtf(s), EPSV);
        v = fmaf(v, inv, bk);
        float mx = v;
        #pragma unroll
        for (int m = 1; m <= 32; m <<= 1) mx = fmaxf(mx, __shfl_xor(mx, m, 64));
        float e = __expf(v - mx);
        float se = e;
        #pragma unroll
        for (int m = 1; m <= 32; m <<= 1) se += __shfl_xor(se, m, 64);
        float a = e / se;
        av[i] = f2bf(a * inv);
        asl += a;
    }
    atomicAdd(&asum[t * 64 + L], asl);
    ushort4 st; st.x = av[0]; st.y = av[1]; st.z = av[2]; st.w = av[3];
    *reinterpret_cast<ushort4*>(aT + ((size_t)t * 64 + L) * NA_ + n0 + w * 4) = st;
}

// vlad[t][k][c] = sum_n ahat[k][n]*xbn[c][n] - asum[k]*cent[k][c]; g2[t][k] = sum_c v^2.
// grid (32, 30), 256 thr. Block: 16 c x 64 k; n-reduction split over 4 waves. No clamps
// (xbn/aT zero-padded to NA_).
__global__ __launch_bounds__(256) void k_vlad(
    const unsigned short* __restrict__ xbn, const unsigned short* __restrict__ aT,
    const float* __restrict__ asum, const float* __restrict__ cent,
    float* __restrict__ vlad, float* __restrict__ g2)
{
    __shared__ float red[4][16 * 68];
    int t = blockIdx.y, c0 = blockIdx.x * 16;
    int tid = threadIdx.x;
    int w = tid >> 6, L = tid & 63, lid = L & 15, quad = L >> 4;

    f32x4 acc[4];
    #pragma unroll
    for (int mt = 0; mt < 4; ++mt)
        #pragma unroll
        for (int r = 0; r < 4; ++r) acc[mt][r] = 0.f;

    const unsigned short* xr = xbn + ((size_t)t * C_ + c0 + lid) * NA_ + quad * 8;
    const unsigned short* ab = aT + (size_t)t * 64 * NA_ + quad * 8;

    #pragma unroll 2
    for (int s = w; s < 25; s += 4) {
        int nb = s * 32;
        bf16x8 bb = *reinterpret_cast<const bf16x8*>(xr + nb);
        #pragma unroll
        for (int mt = 0; mt < 4; ++mt) {
            bf16x8 af = *reinterpret_cast<const bf16x8*>(ab + (size_t)(mt * 16 + lid) * NA_ + nb);
            acc[mt] = __builtin_amdgcn_mfma_f32_16x16x32_bf16(af, bb, acc[mt], 0, 0, 0);
        }
    }
    {
        float* rp = &red[w][0];
        #pragma unroll
        for (int mt = 0; mt < 4; ++mt)
            *reinterpret_cast<f32x4*>(&rp[lid * 68 + mt * 16 + quad * 4]) = acc[mt];
    }
    __syncthreads();

    // epilogue: thread -> k = tid>>2, 4 c
    int k = tid >> 2, cs4 = (tid & 3) * 4;
    float as = asum[t * 64 + k];
    float4 cv = *reinterpret_cast<const float4*>(cent + k * C_ + c0 + cs4);
    float4 vout;
    float s2 = 0.f;
    #pragma unroll
    for (int j = 0; j < 4; ++j) {
        int cc = cs4 + j;
        float v = red[0][cc * 68 + k] + red[1][cc * 68 + k]
                + red[2][cc * 68 + k] + red[3][cc * 68 + k];
        v -= as * ((const float*)&cv)[j];
        ((float*)&vout)[j] = v;
        s2 = fmaf(v, v, s2);
    }
    *reinterpret_cast<float4*>(vlad + ((size_t)t * 64 + k) * C_ + c0 + cs4) = vout;
    s2 += __shfl_xor(s2, 1, 64);
    s2 += __shfl_xor(s2, 2, 64);
    if ((tid & 3) == 0) atomicAdd(&g2[t * 64 + k], s2);
}

// out[k*512+c] = sum_t vlad * inv_intra * inv_g  (norm factors from g2)
__global__ __launch_bounds__(256) void k_out(
    const float* __restrict__ vlad, const float* __restrict__ g2,
    float* __restrict__ out)
{
    __shared__ float intr[1920];
    __shared__ float gl[1920];
    __shared__ float sinv[T_];
    int tid = threadIdx.x;
    for (int i = tid; i < 1920; i += 256) {
        float s = g2[i];
        gl[i] = s;
        intr[i] = 1.0f / fmaxf(sqrtf(s), EPSV);
    }
    __syncthreads();
    if (tid < T_) {
        float s = 0.f;
        #pragma unroll 8
        for (int k = 0; k < 64; ++k) {
            float iv = intr[tid * 64 + k];
            s += gl[tid * 64 + k] * iv * iv;
        }
        sinv[tid] = 1.0f / fmaxf(sqrtf(s), EPSV);
    }
    __syncthreads();
    int idx = blockIdx.x * 256 + tid;  // k*512+c
    int k = idx >> 9;
    float s = 0.f;
    #pragma unroll 5
    for (int t = 0; t < T_; ++t)
        s += vlad[(size_t)t * 32768 + idx] * intr[t * 64 + k] * sinv[t];
    out[idx] = s;
}

extern "C" void kernel_launch(void* const* d_in, const int* in_sizes, int n_in,
                              void* d_out, int out_size, void* d_ws, size_t ws_size,
                              hipStream_t stream) {
    const float* x    = (const float*)d_in[0];   // 30*512*784
    const float* cent = (const float*)d_in[1];   // 64*512
    const float* w    = (const float*)d_in[2];   // 64*512
    const float* b    = (const float*)d_in[3];   // 64
    float* out = (float*)d_out;

    char* p = (char*)d_ws;
    unsigned short* wh = (unsigned short*)p;  p += 65536;
    unsigned short* wl = (unsigned short*)p;  p += 65536;
    float* sumsq = (float*)p;                 p += 30 * 784 * 4;               // 94080
    float* asum  = (float*)p;                 p += 1920 * 4;
    float* g2    = (float*)p;                 p += 1920 * 4;
    unsigned short* aT  = (unsigned short*)p; p += (size_t)T_ * 64 * NA_ * 2;  // 3,072,000
    unsigned short* xh  = (unsigned short*)p; p += (size_t)T_ * NP_ * C_ * 2;  // 25,559,040
    unsigned short* xl  = (unsigned short*)p; p += (size_t)T_ * NP_ * C_ * 2;  // 25,559,040
    unsigned short* xbn = (unsigned short*)p; p += (size_t)T_ * C_ * NA_ * 2;  // 24,576,000
    float* vlad = (float*)p;                  p += (size_t)T_ * 64 * C_ * 4;   // 3,932,160
    // total ~= 83 MB

    k_prep<<<128, 256, 0, stream>>>(w, wh, wl);
    // sumsq + asum + g2 are contiguous: one memset
    hipMemsetAsync(sumsq, 0, (30 * 784 + 2 * 1920) * 4, stream);
    hipMemsetAsync(aT, 0, (size_t)T_ * 64 * NA_ * 2, stream);  // zero incl. n tail
    k_trans<<<dim3(13, 8, T_), 256, 0, stream>>>(x, xh, xl, xbn, sumsq);
    k_assign<<<dim3(49, T_), 256, 0, stream>>>(xh, xl, wh, wl, b, sumsq, aT, asum);
    k_vlad<<<dim3(32, T_), 256, 0, stream>>>(xbn, aT, asum, cent, vlad, g2);
    k_out<<<128, 256, 0, stream>>>(vlad, g2, out);
}

// Round 7
// 155.202 us; speedup vs baseline: 1.0510x; 1.0510x over previous
//
#include <hip/hip_runtime.h>
#include <math.h>

#define T_ 30
#define C_ 512
#define N_ 784      // 28*28; 13 n-tiles of 64
#define NA_ 832     // aT n-pitch (26 ksteps of 32; fully written by k_assign)
#define PITCH 129   // LDS packed-tile pitch in uints (odd -> <=2-way banks)
#define EPSV 1e-12f

typedef __attribute__((ext_vector_type(8))) short bf16x8;
typedef __attribute__((ext_vector_type(4))) float f32x4;
typedef __attribute__((ext_vector_type(4))) int i32x4;

__device__ __forceinline__ unsigned short f2bf(float f) {
    union { float f; unsigned int u; } v; v.f = f;
    unsigned int r = (v.u + 0x7FFFu + ((v.u >> 16) & 1u)) >> 16;  // RNE
    return (unsigned short)r;
}
__device__ __forceinline__ float bf2f(unsigned short h) {
    union { unsigned int u; float f; } v; v.u = ((unsigned int)h) << 16;
    return v.f;
}

// wh/wl: split-precision bf16 of w, layout [k][c]
__global__ void k_prep(const float* __restrict__ w, unsigned short* __restrict__ wh,
                       unsigned short* __restrict__ wl) {
    int idx = blockIdx.x * 256 + threadIdx.x;  // 0..32767
    float v = w[idx];
    unsigned short h = f2bf(v);
    wh[idx] = h;
    wl[idx] = f2bf(v - bf2f(h));
}

// Fused invnorm + logits (3-product split-bf16 MFMA) + softmax + aT + asum.
// grid (13, 30), 256 thr. Block: 64 n x 64 k; c processed in 4 chunks of 128.
// Wave w owns n-slice w*16..w*16+15 for ALL c -> in-wave accumulators, in-wave softmax.
// x read coalesced: per wave-instr 4 rows x 256 B segments.
__global__ __launch_bounds__(256) void k_assign(
    const float* __restrict__ x, const unsigned short* __restrict__ wh,
    const unsigned short* __restrict__ wl, const float* __restrict__ b,
    unsigned short* __restrict__ aT, float* __restrict__ asum)
{
    __shared__ unsigned int xpk[64 * PITCH];   // [n-local][c-chunk-local] packed hi|lo
    __shared__ float ssq[64];
    int t = blockIdx.y, n0 = blockIdx.x * 64;
    int tid = threadIdx.x;
    int w = tid >> 6, L = tid & 63, lid = L & 15, quad = L >> 4;
    int nseg = (tid & 15) * 4;   // n-local group of 4
    int crow = tid >> 4;         // 0..15

    if (tid < 64) ssq[tid] = 0.f;
    float ss[4] = {0.f, 0.f, 0.f, 0.f};

    f32x4 acc[4];
    #pragma unroll
    for (int mt = 0; mt < 4; ++mt)
        #pragma unroll
        for (int r = 0; r < 4; ++r) acc[mt][r] = 0.f;

    for (int cc = 0; cc < 4; ++cc) {
        // ---- stage 128 c x 64 n: read fp32 (coalesced), pack hi|lo uint -> LDS
        #pragma unroll
        for (int p = 0; p < 8; ++p) {
            int cl = p * 16 + crow;            // c within chunk
            int c = cc * 128 + cl;
            int n = n0 + nseg;
            float4 q = make_float4(0.f, 0.f, 0.f, 0.f);
            if (n < N_)  // N_ multiple of 4: float4 fully valid or fully out
                q = *reinterpret_cast<const float4*>(x + ((size_t)t * C_ + c) * N_ + n);
            float vv[4] = {q.x, q.y, q.z, q.w};
            #pragma unroll
            for (int j = 0; j < 4; ++j) {
                float v = vv[j];
                ss[j] = fmaf(v, v, ss[j]);
                union { float f; unsigned int u; } cv; cv.f = v;
                unsigned int hiw = cv.u & 0xFFFF0000u;        // truncated bf16 hi
                union { unsigned int u; float f; } hv; hv.u = hiw;
                unsigned int lo = f2bf(v - hv.f);             // RNE residual
                xpk[(nseg + j) * PITCH + cl] = hiw | lo;
            }
        }
        if (cc == 3) {   // sumsq: reduce over crow (within wave), then across waves
            #pragma unroll
            for (int j = 0; j < 4; ++j) {
                ss[j] += __shfl_xor(ss[j], 16, 64);
                ss[j] += __shfl_xor(ss[j], 32, 64);
            }
            if ((tid & 48) == 0) {
                #pragma unroll
                for (int j = 0; j < 4; ++j) atomicAdd(&ssq[nseg + j], ss[j]);
            }
        }
        __syncthreads();
        // ---- MFMA: 4 ksteps of 32 c
        #pragma unroll
        for (int ks = 0; ks < 4; ++ks) {
            int cl0 = ks * 32 + quad * 8;
            unsigned int u[8];
            #pragma unroll
            for (int e = 0; e < 8; ++e)
                u[e] = xpk[(w * 16 + lid) * PITCH + cl0 + e];
            union { i32x4 v; bf16x8 b; } bh, bl;
            #pragma unroll
            for (int e2 = 0; e2 < 4; ++e2) {
                bh.v[e2] = (int)((u[2 * e2] >> 16) | (u[2 * e2 + 1] & 0xFFFF0000u));
                bl.v[e2] = (int)((u[2 * e2] & 0xFFFFu) | (u[2 * e2 + 1] << 16));
            }
            int cs = cc * 128 + ks * 32 + quad * 8;
            #pragma unroll
            for (int mt = 0; mt < 4; ++mt) {
                bf16x8 ah = *reinterpret_cast<const bf16x8*>(wh + (size_t)(mt * 16 + lid) * C_ + cs);
                bf16x8 al = *reinterpret_cast<const bf16x8*>(wl + (size_t)(mt * 16 + lid) * C_ + cs);
                acc[mt] = __builtin_amdgcn_mfma_f32_16x16x32_bf16(ah, bh.b, acc[mt], 0, 0, 0);
                acc[mt] = __builtin_amdgcn_mfma_f32_16x16x32_bf16(al, bh.b, acc[mt], 0, 0, 0);
                acc[mt] = __builtin_amdgcn_mfma_f32_16x16x32_bf16(ah, bl.b, acc[mt], 0, 0, 0);
            }
        }
        __syncthreads();
    }

    // ---- epilogue (in-wave): lane holds n = n0 + w*16 + lid, k = mt*16 + quad*4 + r
    int n_lane = n0 + w * 16 + lid;
    bool valid = n_lane < N_;
    float inv = 0.f;
    if (valid) inv = 1.0f / fmaxf(sqrtf(ssq[w * 16 + lid]), EPSV);

    float lg[16];
    float mx = -1e30f;
    #pragma unroll
    for (int mt = 0; mt < 4; ++mt) {
        f32x4 bv = *reinterpret_cast<const f32x4*>(b + mt * 16 + quad * 4);
        #pragma unroll
        for (int r = 0; r < 4; ++r) {
            float v = fmaf(acc[mt][r], inv, bv[r]);
            lg[mt * 4 + r] = v;
            mx = fmaxf(mx, v);
        }
    }
    mx = fmaxf(mx, __shfl_xor(mx, 16, 64));
    mx = fmaxf(mx, __shfl_xor(mx, 32, 64));
    float se = 0.f;
    #pragma unroll
    for (int u = 0; u < 16; ++u) { lg[u] = __expf(lg[u] - mx); se += lg[u]; }
    se += __shfl_xor(se, 16, 64);
    se += __shfl_xor(se, 32, 64);
    float rs = 1.0f / se;

    size_t abase = (size_t)t * 64 * NA_ + n_lane;
    #pragma unroll
    for (int mt = 0; mt < 4; ++mt)
        #pragma unroll
        for (int r = 0; r < 4; ++r) {
            int k = mt * 16 + quad * 4 + r;
            float a = lg[mt * 4 + r] * rs;
            aT[abase + (size_t)k * NA_] = valid ? f2bf(a * inv) : (unsigned short)0;
            float ak = valid ? a : 0.f;
            ak += __shfl_xor(ak, 1, 64); ak += __shfl_xor(ak, 2, 64);
            ak += __shfl_xor(ak, 4, 64); ak += __shfl_xor(ak, 8, 64);
            if (lid == 0) atomicAdd(&asum[t * 64 + k], ak);
        }
}

// vlad[t][k][c] = sum_n ahat[k][n]*x[c][n] - asum[k]*cent[k][c]; g2[t][k] = sum_c v^2.
// grid (32, 30), 256 thr. Block: 16 c x 64 k; n-reduction split over 4 waves.
// x re-read hits L3 (just read by k_assign).
__global__ __launch_bounds__(256) void k_vlad(
    const float* __restrict__ x, const unsigned short* __restrict__ aT,
    const float* __restrict__ asum, const float* __restrict__ cent,
    float* __restrict__ vlad, float* __restrict__ g2)
{
    __shared__ float red[4][16 * 68];
    int t = blockIdx.y, c0 = blockIdx.x * 16;
    int tid = threadIdx.x;
    int w = tid >> 6, L = tid & 63, lid = L & 15, quad = L >> 4;

    f32x4 acc[4];
    #pragma unroll
    for (int mt = 0; mt < 4; ++mt)
        #pragma unroll
        for (int r = 0; r < 4; ++r) acc[mt][r] = 0.f;

    const float* xrow = x + ((size_t)t * C_ + c0 + lid) * N_;
    const unsigned short* ab = aT + (size_t)t * 64 * NA_;

    for (int s = w; s < 26; s += 4) {
        int nb = s * 32 + quad * 8;
        int nbc = nb > 776 ? 776 : nb;   // clamped lanes multiply aT zeros
        float4 x0 = *reinterpret_cast<const float4*>(xrow + nbc);
        float4 x1 = *reinterpret_cast<const float4*>(xrow + nbc + 4);
        bf16x8 bb;
        bb[0] = (short)f2bf(x0.x); bb[1] = (short)f2bf(x0.y);
        bb[2] = (short)f2bf(x0.z); bb[3] = (short)f2bf(x0.w);
        bb[4] = (short)f2bf(x1.x); bb[5] = (short)f2bf(x1.y);
        bb[6] = (short)f2bf(x1.z); bb[7] = (short)f2bf(x1.w);
        #pragma unroll
        for (int mt = 0; mt < 4; ++mt) {
            bf16x8 af = *reinterpret_cast<const bf16x8*>(ab + (size_t)(mt * 16 + lid) * NA_ + nb);
            acc[mt] = __builtin_amdgcn_mfma_f32_16x16x32_bf16(af, bb, acc[mt], 0, 0, 0);
        }
    }
    {
        float* rp = &red[w][0];
        #pragma unroll
        for (int mt = 0; mt < 4; ++mt)
            *reinterpret_cast<f32x4*>(&rp[lid * 68 + mt * 16 + quad * 4]) = acc[mt];
    }
    __syncthreads();

    // epilogue: thread -> k = tid>>2, 4 c
    int k = tid >> 2, cs4 = (tid & 3) * 4;
    float as = asum[t * 64 + k];
    float4 cv = *reinterpret_cast<const float4*>(cent + k * C_ + c0 + cs4);
    float4 vout;
    float s2 = 0.f;
    #pragma unroll
    for (int j = 0; j < 4; ++j) {
        int cc = cs4 + j;
        float v = red[0][cc * 68 + k] + red[1][cc * 68 + k]
                + red[2][cc * 68 + k] + red[3][cc * 68 + k];
        v -= as * ((const float*)&cv)[j];
        ((float*)&vout)[j] = v;
        s2 = fmaf(v, v, s2);
    }
    *reinterpret_cast<float4*>(vlad + ((size_t)t * 64 + k) * C_ + c0 + cs4) = vout;
    s2 += __shfl_xor(s2, 1, 64);
    s2 += __shfl_xor(s2, 2, 64);
    if ((tid & 3) == 0) atomicAdd(&g2[t * 64 + k], s2);
}

// out[k*512+c] = sum_t vlad * inv_intra * inv_g  (norm factors from g2)
__global__ __launch_bounds__(256) void k_out(
    const float* __restrict__ vlad, const float* __restrict__ g2,
    float* __restrict__ out)
{
    __shared__ float intr[1920];
    __shared__ float sinv[T_];
    int tid = threadIdx.x;
    for (int i = tid; i < 1920; i += 256)
        intr[i] = 1.0f / fmaxf(sqrtf(g2[i]), EPSV);
    __syncthreads();
    if (tid < T_) {
        float s = 0.f;
        #pragma unroll 8
        for (int k = 0; k < 64; ++k) {
            float iv = intr[tid * 64 + k];
            s += g2[tid * 64 + k] * iv * iv;
        }
        sinv[tid] = 1.0f / fmaxf(sqrtf(s), EPSV);
    }
    __syncthreads();
    int idx = blockIdx.x * 256 + tid;  // k*512+c
    int k = idx >> 9;
    float s = 0.f;
    #pragma unroll 5
    for (int t = 0; t < T_; ++t)
        s += vlad[(size_t)t * 32768 + idx] * intr[t * 64 + k] * sinv[t];
    out[idx] = s;
}

extern "C" void kernel_launch(void* const* d_in, const int* in_sizes, int n_in,
                              void* d_out, int out_size, void* d_ws, size_t ws_size,
                              hipStream_t stream) {
    const float* x    = (const float*)d_in[0];   // 30*512*784
    const float* cent = (const float*)d_in[1];   // 64*512
    const float* w    = (const float*)d_in[2];   // 64*512
    const float* b    = (const float*)d_in[3];   // 64
    float* out = (float*)d_out;

    char* p = (char*)d_ws;
    unsigned short* wh = (unsigned short*)p;  p += 65536;
    unsigned short* wl = (unsigned short*)p;  p += 65536;
    float* asum = (float*)p;                  p += 1920 * 4;
    float* g2   = (float*)p;                  p += 1920 * 4;
    unsigned short* aT = (unsigned short*)p;  p += (size_t)T_ * 64 * NA_ * 2;  // 3,194,880
    float* vlad = (float*)p;                  p += (size_t)T_ * 64 * C_ * 4;   // 3,932,160
    // total ~= 7.3 MB

    k_prep<<<128, 256, 0, stream>>>(w, wh, wl);
    hipMemsetAsync(asum, 0, 2 * 1920 * 4, stream);   // asum + g2 contiguous
    k_assign<<<dim3(13, T_), 256, 0, stream>>>(x, wh, wl, b, aT, asum);
    k_vlad<<<dim3(32, T_), 256, 0, stream>>>(x, aT, asum, cent, vlad, g2);
    k_out<<<128, 256, 0, stream>>>(vlad, g2, out);
}